// Round 2
// 855.395 us; speedup vs baseline: 1.2175x; 1.2175x over previous
//
#include <hip/hip_runtime.h>

// Problem constants (AttnMLP): x [8,2048,2048] fp32 -> 16384 rows of D=2048.
#define D_EMBD 2048
#define MROWS  16384
#define BM     256
#define BN     256

typedef _Float16 f16x8 __attribute__((ext_vector_type(8)));
typedef _Float16 f16x4 __attribute__((ext_vector_type(4)));
typedef float    f32x4 __attribute__((ext_vector_type(4)));

__device__ __forceinline__ float fast_gelu(float x) {
    // 0.5*x*(1+tanh(sqrt(2/pi)*(x+0.044715 x^3))), tanh via exp (v_exp_f32)
    float u = 0.7978845608028654f * (x + 0.044715f * x * x * x);
    float e = __expf(2.0f * u);
    float t = 1.0f - 2.0f / (e + 1.0f);   // == tanh(u), saturates at +/-inf
    return 0.5f * x * (1.0f + t);
}

// Async 16B global->LDS copy. LDS dest must be wave-uniform base + lane*16.
__device__ __forceinline__ void async16(const void* g, void* l) {
    __builtin_amdgcn_global_load_lds(
        (const __attribute__((address_space(1))) unsigned int*)g,
        (__attribute__((address_space(3))) unsigned int*)l, 16, 0, 0);
}

// ---------------------------------------------------------------------------
// W fp32 (N x K = torch (out,in)) -> fp16, one layer slice (2048x2048).
// ---------------------------------------------------------------------------
__global__ __launch_bounds__(256) void convert_w(const float* __restrict__ W,
                                                 _Float16* __restrict__ Wh) {
    const int i = blockIdx.x * 256 + threadIdx.x;
    const float4* src = (const float4*)W;
    float4 a = src[i * 2];
    float4 b = src[i * 2 + 1];
    f16x8 p;
    p[0] = (_Float16)a.x; p[1] = (_Float16)a.y; p[2] = (_Float16)a.z; p[3] = (_Float16)a.w;
    p[4] = (_Float16)b.x; p[5] = (_Float16)b.y; p[6] = (_Float16)b.z; p[7] = (_Float16)b.w;
    ((f16x8*)Wh)[i] = p;
}

// ---------------------------------------------------------------------------
// LayerNorm over D=2048 -> fp16. One block (256 thr) per row, 8 elems/thread.
// ---------------------------------------------------------------------------
__device__ __forceinline__ void ln_core(float v[8], const float* w,
                                        const float* bln, _Float16* H,
                                        int row, int tid) {
    float s = 0.f, sq = 0.f;
    #pragma unroll
    for (int i = 0; i < 8; i++) { s += v[i]; sq = fmaf(v[i], v[i], sq); }

    #pragma unroll
    for (int off = 32; off > 0; off >>= 1) {
        s  += __shfl_down(s, off);
        sq += __shfl_down(sq, off);
    }

    __shared__ float red[8];
    __shared__ float stats[2];
    const int wv = tid >> 6, ln = tid & 63;
    if (ln == 0) { red[wv] = s; red[4 + wv] = sq; }
    __syncthreads();
    if (tid == 0) {
        float ts = (red[0] + red[1]) + (red[2] + red[3]);
        float tq = (red[4] + red[5]) + (red[6] + red[7]);
        float mean = ts * (1.0f / D_EMBD);
        float var  = tq * (1.0f / D_EMBD) - mean * mean;
        stats[0] = mean;
        stats[1] = rsqrtf(var + 1e-5f);
    }
    __syncthreads();
    const float mean = stats[0], rstd = stats[1];

    float4 w0 = ((const float4*)w)[tid * 2],   w1 = ((const float4*)w)[tid * 2 + 1];
    float4 b0 = ((const float4*)bln)[tid * 2], b1 = ((const float4*)bln)[tid * 2 + 1];
    const float ww[8] = {w0.x, w0.y, w0.z, w0.w, w1.x, w1.y, w1.z, w1.w};
    const float bb[8] = {b0.x, b0.y, b0.z, b0.w, b1.x, b1.y, b1.z, b1.w};

    f16x8 p;
    #pragma unroll
    for (int i = 0; i < 8; i++)
        p[i] = (_Float16)fmaf((v[i] - mean) * rstd, ww[i], bb[i]);
    ((f16x8*)(H + (size_t)row * D_EMBD))[tid] = p;
}

__global__ __launch_bounds__(256) void ln_f32(const float* __restrict__ X,
                                              const float* __restrict__ w,
                                              const float* __restrict__ bln,
                                              _Float16* __restrict__ H) {
    const int row = blockIdx.x, tid = threadIdx.x;
    const float* xr = X + (size_t)row * D_EMBD;
    float4 v0 = ((const float4*)xr)[tid * 2];
    float4 v1 = ((const float4*)xr)[tid * 2 + 1];
    float v[8] = {v0.x, v0.y, v0.z, v0.w, v1.x, v1.y, v1.z, v1.w};
    ln_core(v, w, bln, H, row, tid);
}

__global__ __launch_bounds__(256) void ln_f16(const _Float16* __restrict__ X,
                                              const float* __restrict__ w,
                                              const float* __restrict__ bln,
                                              _Float16* __restrict__ H) {
    const int row = blockIdx.x, tid = threadIdx.x;
    f16x8 h = ((const f16x8*)(X + (size_t)row * D_EMBD))[tid];
    float v[8];
    #pragma unroll
    for (int i = 0; i < 8; i++) v[i] = (float)h[i];
    ln_core(v, w, bln, H, row, tid);
}

// ---------------------------------------------------------------------------
// C[m][n] = gelu( sum_k A[m][k]*B[n][k] + bias[n] ),  B = W (out,in).
// 256x256 tile, BK=64, 512 thr = 8 waves (2Mx4N), per-wave 128x64 output via
// acc[8][4] of 16x16x32 f16 MFMA.  8-phase (4/K-tile) schedule, double-buffered
// LDS capped at EXACTLY 128 KiB (HW-proven size; round-1 fix: 136 KiB static
// LDS was the prime launch-failure suspect).  Counted vmcnt(4) (never 0 in
// main loop), setprio around MFMA.  Epilogue REUSES K-loop LDS (wave-private
// slices, single barrier).
//
// LDS tile layout per (buf b, k-half s): 256 rows x 4 16B-chunks, chunk c of
// row r stored at position p = c ^ ((r>>1)&3); read pos q ^ ((c16>>1)&3) is
// lane-row-consistent because fragment rows differ only in c16 (mod-4-even
// bases), giving back chunk q.  Verified 0 bank conflicts in the 128x128
// predecessor with the same involution family.
//
// Wait/overwrite invariants (per wave, halves staged 1/phase in order
// A0,B0,A1,B1 of tile t+1 during tile t):
//   ph2 vmcnt(4): outstanding [A1_t,B1_t,A0_{t+1},B0_{t+1}] -> A1_t,B1_t done
//                 before ph3 reads them (vmcnt precedes the barrier, so the
//                 barrier publishes all waves' completions).
//   ph4 vmcnt(4): outstanding [A0..B1 of t+1] -> A0,B0 of t+1 done before
//                 next-iter ph1 reads them.
//   Every region's last ds_read completes (LGKM0) >=3 barriers before its
//   overwrite is issued -> no cross-wave overwrite race.
// ---------------------------------------------------------------------------
#define SBAR() do { __builtin_amdgcn_sched_barrier(0); \
                    __builtin_amdgcn_s_barrier(); \
                    __builtin_amdgcn_sched_barrier(0); } while (0)
#define LGKM0() do { asm volatile("s_waitcnt lgkmcnt(0)" ::: "memory"); \
                     __builtin_amdgcn_sched_barrier(0); } while (0)
#define VMCNT(n) asm volatile("s_waitcnt vmcnt(" #n ")" ::: "memory")

#define MM(JB) do { \
    __builtin_amdgcn_s_setprio(1); \
    _Pragma("unroll") \
    for (int i_ = 0; i_ < 8; i_++) { \
        acc[i_][JB]     = __builtin_amdgcn_mfma_f32_16x16x32_f16(af[i_], bf[0], acc[i_][JB], 0, 0, 0); \
        acc[i_][JB + 1] = __builtin_amdgcn_mfma_f32_16x16x32_f16(af[i_], bf[1], acc[i_][JB + 1], 0, 0, 0); \
    } \
    __builtin_amdgcn_s_setprio(0); \
} while (0)

template <typename OutT>
__global__ __launch_bounds__(512, 2) void gemm_bias_gelu(
    const _Float16* __restrict__ A,   // rows x K fp16 (LN output chunk)
    const _Float16* __restrict__ B,   // N x K fp16 (W layer)
    const float* __restrict__ bias,   // N fp32
    OutT* __restrict__ C)             // rows x N (float or _Float16)
{
    constexpr int K  = D_EMBD;
    constexpr int N  = D_EMBD;
    constexpr int NT = K / 64;        // 32 K-tiles

    // EXACTLY 128 KiB.  K-loop: [0,65536) halves; fp16 epilogue reuses it.
    __shared__ _Float16 smem[65536];

    const int tid  = threadIdx.x;
    const int wave = tid >> 6, lane = tid & 63;
    const int wm = wave >> 2, wn = wave & 3;      // 2x4 wave grid, 128x64 each
    const int q = lane >> 4, c16 = lane & 15;
    const int m0 = blockIdx.x * BM;
    const int n0 = blockIdx.y * BN;

    const _Float16* Ab = A + (size_t)m0 * K;
    const _Float16* Bb = B + (size_t)n0 * K;

    // Staging geometry: per 16B instr, LDS row = tid>>2, pos = tid&3 of a
    // 128-row half-region; source chunk = pos ^ ((row>>1)&3) (pre-swizzled).
    const int srow = tid >> 2;                                // 0..127
    const int sq   = ((tid & 3) ^ ((tid >> 3) & 3)) * 8;      // halves

    // Fragment-read geometry: pos = q ^ ((c16>>1)&3), lane-invariant over frags.
    const int rpos = (q ^ ((c16 >> 1) & 3)) * 8;              // halves
    const int arow = wm * 128 + c16;
    const int brow = wn * 64 + c16;

    f32x4 acc[8][4] = {};
    f16x8 af[8], bf[2];

    // LDS half-region bases (in halves): A(b,s) = b*32768 + s*8192
    //                                    B(b,s) = b*32768 + 16384 + s*8192
    auto stageA = [&](int b, int s, int k0) {
        const _Float16* g = Ab + (size_t)srow * K + (k0 + s * 32 + sq);
        _Float16* l = &smem[b * 32768 + s * 8192 + tid * 8];
        async16(g, l);
        async16(g + (size_t)128 * K, l + 4096);
    };
    auto stageB = [&](int b, int s, int k0) {
        const _Float16* g = Bb + (size_t)srow * K + (k0 + s * 32 + sq);
        _Float16* l = &smem[b * 32768 + 16384 + s * 8192 + tid * 8];
        async16(g, l);
        async16(g + (size_t)128 * K, l + 4096);
    };
    auto rdA = [&](int b, int s) {
        const int base = b * 32768 + s * 8192 + arow * 32 + rpos;
        #pragma unroll
        for (int i = 0; i < 8; i++)
            af[i] = *(const f16x8*)&smem[base + i * 512];
    };
    auto rdB = [&](int b, int s, int jb) {
        const int base = b * 32768 + 16384 + s * 8192 + brow * 32 + rpos;
        bf[0] = *(const f16x8*)&smem[base + jb * 512];
        bf[1] = *(const f16x8*)&smem[base + jb * 512 + 512];
    };

    // Prologue: stage tile 0 (order A0,B0,A1,B1); A0,B0 guaranteed, A1,B1 fly.
    stageA(0, 0, 0); stageB(0, 0, 0); stageA(0, 1, 0); stageB(0, 1, 0);
    VMCNT(4);
    SBAR();

    for (int t = 0; t < NT - 1; ++t) {
        const int b = t & 1, nb = b ^ 1;
        const int nk0 = (t + 1) * 64;
        // ph1: (k-half0, Nf0-1); stage A0 of t+1
        rdA(b, 0); rdB(b, 0, 0);
        stageA(nb, 0, nk0);
        SBAR();
        LGKM0();
        MM(0);
        // ph2: (k-half0, Nf2-3); stage B0 of t+1; ensure A1,B1 of t landed
        rdB(b, 0, 2);
        stageB(nb, 0, nk0);
        VMCNT(4);
        SBAR();
        LGKM0();
        MM(2);
        // ph3: (k-half1, Nf0-1); stage A1 of t+1
        rdA(b, 1); rdB(b, 1, 0);
        stageA(nb, 1, nk0);
        SBAR();
        LGKM0();
        MM(0);
        // ph4: (k-half1, Nf2-3); stage B1 of t+1; ensure A0,B0 of t+1 landed
        rdB(b, 1, 2);
        stageB(nb, 1, nk0);
        VMCNT(4);
        SBAR();
        LGKM0();
        MM(2);
    }

    // Tail tile (no staging; drain remaining A1,B1 with vmcnt(0) once).
    {
        const int b = (NT - 1) & 1;
        rdA(b, 0); rdB(b, 0, 0);
        LGKM0();
        MM(0);
        rdB(b, 0, 2);
        VMCNT(0);
        SBAR();
        LGKM0();
        MM(2);
        rdA(b, 1); rdB(b, 1, 0);
        LGKM0();
        MM(0);
        rdB(b, 1, 2);
        LGKM0();
        MM(2);
    }

    // Epilogue. C/D layout: col = c16, row = q*4 + r within each 16x16 frag.
    float bv[4];
    #pragma unroll
    for (int j = 0; j < 4; j++) bv[j] = bias[n0 + wn * 64 + j * 16 + c16];

    if constexpr (sizeof(OutT) == 2) {
        // Reuse K-loop LDS: wave-private 8192-half slice, two 64-row passes
        // (64 rows x 68-half stride = 4352 halves/pass).  Row stride 68
        // (136 B) spreads write banks (row*2 term) and keeps the 2x b64/lane
        // read near the structural minimum.  One block barrier: after it no
        // wave touches another wave's slice, so no further barriers needed
        // (same-wave ds_write->ds_read ordering is compiler-handled).
        SBAR();   // all waves done with K-loop LDS reads
        _Float16* eb = &smem[wave * 8192];
        const int rr0 = lane >> 3, ch = lane & 7;
        #pragma unroll
        for (int pass = 0; pass < 2; ++pass) {
            #pragma unroll
            for (int i = 0; i < 4; i++) {
                const int ii = pass * 4 + i;
                #pragma unroll
                for (int j = 0; j < 4; j++)
                    #pragma unroll
                    for (int r = 0; r < 4; r++)
                        eb[(i * 16 + q * 4 + r) * 68 + j * 16 + c16] =
                            (_Float16)fast_gelu(acc[ii][j][r] + bv[j]);
            }
            #pragma unroll
            for (int p = 0; p < 8; p++) {
                const int rr = p * 8 + rr0;      // 0..63 within pass
                f16x4 lo = *(const f16x4*)&eb[rr * 68 + ch * 8];
                f16x4 hi = *(const f16x4*)&eb[rr * 68 + ch * 8 + 4];
                f16x8 v;
                #pragma unroll
                for (int e = 0; e < 4; e++) { v[e] = lo[e]; v[e + 4] = hi[e]; }
                *(f16x8*)&C[(size_t)(m0 + wm * 128 + pass * 64 + rr) * N
                            + (n0 + wn * 64 + ch * 8)] = v;
            }
        }
    } else {
        // fp32: 16-lane groups already store 64 B contiguous segments.
        #pragma unroll
        for (int j = 0; j < 4; j++) {
            const int gcol = n0 + wn * 64 + j * 16 + c16;
            #pragma unroll
            for (int i = 0; i < 8; i++) {
                #pragma unroll
                for (int r = 0; r < 4; r++) {
                    const int grow = m0 + wm * 128 + i * 16 + q * 4 + r;
                    C[(size_t)grow * N + gcol] = (OutT)fast_gelu(acc[i][j][r] + bv[j]);
                }
            }
        }
    }
}

// ---------------------------------------------------------------------------
extern "C" void kernel_launch(void* const* d_in, const int* in_sizes, int n_in,
                              void* d_out, int out_size, void* d_ws, size_t ws_size,
                              hipStream_t stream) {
    const float* x    = (const float*)d_in[0];   // [8,2048,2048] fp32
    const float* W    = (const float*)d_in[1];   // [4,2048,2048] fp32 (out,in)
    const float* bias = (const float*)d_in[2];   // [4,2048]
    const float* lnw  = (const float*)d_in[3];   // [4,2048]
    const float* lnb  = (const float*)d_in[4];   // [4,2048]
    float* out = (float*)d_out;                  // [8,2048,2048] fp32 (128 MiB)

    // fp16 intermediate activations Xh (16384x2048 fp16 = 64 MiB) live in the
    // TOP HALF of d_out: offset 64 MiB, exactly filling [64,128) MiB.
    // Layer-3 overlap proof: chunks ascend; after chunk ending at row E the
    // fp32 writes cover bytes < 8K*E, while unconsumed Xh rows r >= E start at
    // 64Mi + 4K*r >= 8K*E  (<=> E <= 16384, always true). Within a chunk, the
    // LN kernel (stream-ordered) reads Xh rows into H before the GEMM writes
    // fp32 over them. Layers 0-2 rewrite Xh rows in place (GEMM reads H only).
    _Float16* Xh = (_Float16*)((char*)d_out + (size_t)64 * 1024 * 1024);

    // ws: Wh (one layer fp16, 8 MiB) | H (LN-output fp16, chunked to fit).
    // NEVER exceed ws_size.
    const size_t whBytes = (size_t)D_EMBD * D_EMBD * sizeof(_Float16);  // 8 MiB
    _Float16* Wh = (_Float16*)d_ws;
    _Float16* H  = (_Float16*)((char*)d_ws + whBytes);

    const size_t rowBytes = (size_t)D_EMBD * sizeof(_Float16);  // 4 KiB
    long chRows = (ws_size > whBytes) ? (long)((ws_size - whBytes) / rowBytes) : 0;
    chRows = (chRows / BM) * BM;
    if (chRows > MROWS) chRows = MROWS;
    if (chRows < BM)    chRows = BM;

    for (int layer = 0; layer < 4; layer++) {
        convert_w<<<(D_EMBD * D_EMBD) / 2048, 256, 0, stream>>>(
            W + (size_t)layer * D_EMBD * D_EMBD, Wh);
        for (long m = 0; m < MROWS; m += chRows) {
            const long rows = (MROWS - m < chRows) ? (MROWS - m) : chRows;
            if (layer == 0)
                ln_f32<<<(int)rows, 256, 0, stream>>>(
                    x + (size_t)m * D_EMBD, lnw, lnb, H);
            else
                ln_f16<<<(int)rows, 256, 0, stream>>>(
                    Xh + (size_t)m * D_EMBD, lnw + (size_t)layer * D_EMBD,
                    lnb + (size_t)layer * D_EMBD, H);
            dim3 grid((int)(rows / BM), D_EMBD / BN);
            if (layer < 3)
                gemm_bias_gelu<_Float16><<<grid, 512, 0, stream>>>(
                    H, Wh, bias + (size_t)layer * D_EMBD, Xh + (size_t)m * D_EMBD);
            else
                gemm_bias_gelu<float><<<grid, 512, 0, stream>>>(
                    H, Wh, bias + (size_t)layer * D_EMBD, out + (size_t)m * D_EMBD);
        }
    }
}